// Round 5
// baseline (299.534 us; speedup 1.0000x reference)
//
#include <hip/hip_runtime.h>

#define EPS 1e-5f
#define B 16
#define CH 22
#define T_IN 1001
#define F 36
#define RF 65
#define T1 937            // T_IN - RF + 1
#define FC 792            // F*CH
#define KSPLIT 4
#define FCH 198           // FC/KSPLIT
#define FSPLIT 4
#define FH2 9             // F/FSPLIT
#define UN 885            // valid u range for Q/E
#define UT2 128           // qconv u-tile (2 per lane)
#define NU2 7             // ceil(885/128)
#define PS_LEN2 170       // 127 + 3*14 + 1
#define PSTR 944          // P row stride (>= 937 needed by qconv staging)
#define KS 15
#define GN 295
#define WN 129
#define M43 43
#define BF 576            // B*F

// workspace float offsets
#define H2P_OFF 0                 // 4*16*36*937   = 2,158,848
#define P_OFF   2158848           // + 16*36*944   =   543,744
#define EP_OFF  2702592           // + 4*16*36*885 = 2,039,040
#define S_OFF   4741632           // + 16*36*43    =    24,768
#define WTT_OFF 4766400           // + 36*65       =     2,340
#define WST_OFF 4768740           // + 792*36      =    28,512
#define WCT_OFF 4797252           // + 36*15*36    =    19,440
#define H1_OFF  4816704           // h1 (slabbed if scratch is tight)

__device__ __forceinline__ float elu_f(float v) {
    return v > 0.f ? v : (__expf(v) - 1.f);
}

// ---- prep: transpose weights for wave-uniform scalar access ---------------
__global__ __launch_bounds__(256) void k_prep(
    const float* __restrict__ w_t, const float* __restrict__ w_s,
    const float* __restrict__ w_c, float* __restrict__ wtT,
    float* __restrict__ wsT, float* __restrict__ wcT)
{
    int i = blockIdx.x * 256 + threadIdx.x;
    if (i < F * RF)     { int k = i / F,  fi = i % F; wtT[i] = w_t[fi * RF + k]; }
    if (i < FC * F)     { int fc = i / F, fo = i % F; wsT[i] = w_s[fo * FC + fc]; }
    if (i < F * KS * F) { int fk = i / F, fo = i % F; int f = fk / KS, k = fk % KS;
                          wcT[i] = w_c[(fo * F + f) * KS + k]; }
}

// ---- K1a: temporal conv + bn + elu -> h1[b][fc][t] (slab) -----------------
// grid (ceil(TSeff/512), CH, B); 4 waves = 4 fi-groups; lane = t, 8 t per lane
__global__ __launch_bounds__(256) void k_tconv(
    const float* __restrict__ x,   const float* __restrict__ wtT,
    const float* __restrict__ b_t, const float* __restrict__ g_t,
    const float* __restrict__ be_t,const float* __restrict__ m_t,
    const float* __restrict__ v_t, float* __restrict__ h1,
    int t_base, int TS, int TSeff)
{
    const int lane = threadIdx.x & 63;
    const int fi0  = __builtin_amdgcn_readfirstlane((threadIdx.x >> 6) * 9);
    const int b = blockIdx.z, ch = blockIdx.y;
    const int tl0 = blockIdx.x * 512 + lane;
    const float* xrow = x + (b * CH + ch) * T_IN;

    const float* pm[8];
    #pragma unroll
    for (int m = 0; m < 8; ++m) {
        int t = t_base + tl0 + 64 * m;
        int tc = t < (T1 - 1) ? t : (T1 - 1);
        pm[m] = xrow + tc;
    }

    float acc[72];
    #pragma unroll
    for (int i = 0; i < 72; ++i) acc[i] = 0.f;

    #pragma unroll 5
    for (int k = 0; k < RF; ++k) {
        const float* wr = wtT + k * F + fi0;   // 9 consecutive -> wide s_load
        float w0 = wr[0], w1 = wr[1], w2 = wr[2], w3 = wr[3], w4 = wr[4];
        float w5 = wr[5], w6 = wr[6], w7 = wr[7], w8 = wr[8];
        #pragma unroll
        for (int m = 0; m < 8; ++m) {
            float xv = pm[m][k];
            acc[0 * 8 + m] += xv * w0;
            acc[1 * 8 + m] += xv * w1;
            acc[2 * 8 + m] += xv * w2;
            acc[3 * 8 + m] += xv * w3;
            acc[4 * 8 + m] += xv * w4;
            acc[5 * 8 + m] += xv * w5;
            acc[6 * 8 + m] += xv * w6;
            acc[7 * 8 + m] += xv * w7;
            acc[8 * 8 + m] += xv * w8;
        }
    }

    #pragma unroll
    for (int j = 0; j < 9; ++j) {
        int fi = fi0 + j;
        float s1 = g_t[fi] * rsqrtf(v_t[fi] + EPS);
        float o1 = (b_t[fi] - m_t[fi]) * s1 + be_t[fi];
        float* hrow = h1 + ((size_t)(b * F + fi) * CH + ch) * TS;
        #pragma unroll
        for (int m = 0; m < 8; ++m) {
            int tloc = tl0 + 64 * m;
            int t = t_base + tloc;
            if (tloc < TSeff && t < T1)
                hrow[tloc] = elu_f(acc[j * 8 + m] * s1 + o1);
        }
    }
}

// ---- K1b: 1x1 spatial conv, split-K over fc -> raw partials h2p -----------
// grid (ceil(TSeff/256), KSPLIT, B); 4 waves = 4 fo-groups; 4 t per lane
__global__ __launch_bounds__(256) void k_sconv(
    const float* __restrict__ h1,  const float* __restrict__ wsT,
    float* __restrict__ h2p, int t_base, int TS, int TSeff)
{
    const int lane = threadIdx.x & 63;
    const int fo0  = __builtin_amdgcn_readfirstlane((threadIdx.x >> 6) * 9);
    const int slice = blockIdx.y, b = blockIdx.z;
    const int tl0 = blockIdx.x * 256 + lane;

    int off[4];
    #pragma unroll
    for (int m = 0; m < 4; ++m) {
        int tloc = tl0 + 64 * m;
        off[m] = tloc < (TSeff - 1) ? tloc : (TSeff - 1);
    }

    const float* hq = h1 + ((size_t)b * FC + slice * FCH) * TS;
    const float* wb = wsT + slice * FCH * F + fo0;

    float acc[36];
    #pragma unroll
    for (int i = 0; i < 36; ++i) acc[i] = 0.f;

    #pragma unroll 2
    for (int fc = 0; fc < FCH; ++fc) {
        const float* wr = wb + fc * F;         // 9 consecutive -> wide s_load
        float w0 = wr[0], w1 = wr[1], w2 = wr[2], w3 = wr[3], w4 = wr[4];
        float w5 = wr[5], w6 = wr[6], w7 = wr[7], w8 = wr[8];
        #pragma unroll
        for (int m = 0; m < 4; ++m) {
            float hv = hq[off[m]];
            acc[0 * 4 + m] += hv * w0;
            acc[1 * 4 + m] += hv * w1;
            acc[2 * 4 + m] += hv * w2;
            acc[3 * 4 + m] += hv * w3;
            acc[4 * 4 + m] += hv * w4;
            acc[5 * 4 + m] += hv * w5;
            acc[6 * 4 + m] += hv * w6;
            acc[7 * 4 + m] += hv * w7;
            acc[8 * 4 + m] += hv * w8;
        }
        hq += TS;
    }

    #pragma unroll
    for (int j = 0; j < 9; ++j) {
        float* erow = h2p + (((size_t)slice * B + b) * F + fo0 + j) * T1;
        #pragma unroll
        for (int m = 0; m < 4; ++m) {
            int tloc = tl0 + 64 * m;
            int t = t_base + tloc;
            if (tloc < TSeff && t < T1) erow[t] = acc[j * 4 + m];
        }
    }
}

// ---- K1c: combine h2p slices + bn_s + elu + pool3 -> P[b][f][u] -----------
__global__ __launch_bounds__(256) void k_pool(
    const float* __restrict__ h2p, const float* __restrict__ b_s,
    const float* __restrict__ g_s, const float* __restrict__ be_s,
    const float* __restrict__ m_s, const float* __restrict__ v_s,
    float* __restrict__ P)
{
    const int bf = blockIdx.x;
    const int f = bf % F;
    const float s2 = g_s[f] * rsqrtf(v_s[f] + EPS);
    const float o2 = (b_s[f] - m_s[f]) * s2 + be_s[f];
    const float* p0 = h2p + ((size_t)(0 * B) * F + bf) * T1;
    const float* p1 = h2p + ((size_t)(1 * B) * F + bf) * T1;
    const float* p2 = h2p + ((size_t)(2 * B) * F + bf) * T1;
    const float* p3 = h2p + ((size_t)(3 * B) * F + bf) * T1;
    for (int u = threadIdx.x; u < PSTR; u += 256) {
        float a = 0.f;
        #pragma unroll
        for (int d = 0; d < 3; ++d) {
            int s = u + d; if (s > T1 - 1) s = T1 - 1;
            float q = p0[s] + p1[s] + p2[s] + p3[s];
            a += elu_f(q * s2 + o2);
        }
        P[(size_t)bf * PSTR + u] = a * (1.f / 3.f);
    }
}

// ---- K2: dilated conv over P -> raw partials Ep ---------------------------
// grid (NU2, FSPLIT, B); 4 waves = 4 fo-groups; 2 u per lane
__global__ __launch_bounds__(256) void k_qconv(
    const float* __restrict__ P,   const float* __restrict__ wcT,
    float* __restrict__ Ep)
{
    __shared__ float Ps[FH2 * PS_LEN2];   // 6.1 KB
    const int tid = threadIdx.x;
    const int slice = blockIdx.y, b = blockIdx.z;
    const int u0 = blockIdx.x * UT2;
    const int f_base = slice * FH2;

    for (int i = tid; i < FH2 * PS_LEN2; i += 256) {
        int fl = i / PS_LEN2, j = i % PS_LEN2;
        Ps[i] = P[(size_t)(b * F + f_base + fl) * PSTR + u0 + j];
    }
    __syncthreads();

    const int lane = tid & 63;
    const int fo0  = __builtin_amdgcn_readfirstlane((tid >> 6) * 9);

    float acc[18];
    #pragma unroll
    for (int i = 0; i < 18; ++i) acc[i] = 0.f;

    for (int fl = 0; fl < FH2; ++fl) {
        const int pb = fl * PS_LEN2 + lane;
        #pragma unroll
        for (int k = 0; k < KS; ++k) {
            float pv0 = Ps[pb + 3 * k];
            float pv1 = Ps[pb + 64 + 3 * k];
            const float* wr = wcT + ((f_base + fl) * KS + k) * F + fo0;
            #pragma unroll
            for (int j = 0; j < 9; ++j) {
                float w = wr[j];
                acc[j * 2 + 0] += pv0 * w;
                acc[j * 2 + 1] += pv1 * w;
            }
        }
    }
    #pragma unroll
    for (int m = 0; m < 2; ++m) {
        int u_g = u0 + lane + 64 * m;
        if (u_g < UN) {
            #pragma unroll
            for (int j = 0; j < 9; ++j)
                Ep[(((size_t)slice * B + b) * F + fo0 + j) * UN + u_g] = acc[j * 2 + m];
        }
    }
}

// ---- K3: combine Ep + bn_c + elu, window sums -> S ------------------------
__global__ __launch_bounds__(256) void k_wins(
    const float* __restrict__ Ep,  const float* __restrict__ b_c,
    const float* __restrict__ g_c, const float* __restrict__ be_c,
    const float* __restrict__ m_c, const float* __restrict__ v_c,
    float* __restrict__ S)
{
    __shared__ float Es[UN];
    __shared__ float G[GN];
    __shared__ float Ws[WN];
    const int tid = threadIdx.x;
    const int bf = blockIdx.x;
    const int f = bf % F;
    const float sc = g_c[f] * rsqrtf(v_c[f] + EPS);
    const float oc = (b_c[f] - m_c[f]) * sc + be_c[f];
    const float* e0 = Ep + (size_t)bf * UN;
    const float* e1 = Ep + ((size_t)1 * BF + bf) * UN;
    const float* e2 = Ep + ((size_t)2 * BF + bf) * UN;
    const float* e3 = Ep + ((size_t)3 * BF + bf) * UN;
    for (int i = tid; i < UN; i += 256)
        Es[i] = elu_f((e0[i] + e1[i] + e2[i] + e3[i]) * sc + oc);
    __syncthreads();
    for (int q = tid; q < GN; q += 256)
        G[q] = Es[3 * q] + Es[3 * q + 1] + Es[3 * q + 2];
    __syncthreads();
    if (tid < WN) {
        float a = 0.f;
        for (int q = tid; q < tid + 167; ++q) a += G[q];
        Ws[tid] = a;
    }
    __syncthreads();
    if (tid < M43)
        S[bf * M43 + tid] = (Ws[3 * tid] + Ws[3 * tid + 1] + Ws[3 * tid + 2]) * (1.f / 3.f);
}

// ---- K4: FC over summed features ------------------------------------------
__global__ __launch_bounds__(256) void k_fc(
    const float* __restrict__ S, const float* __restrict__ w_fc,
    const float* __restrict__ b_fc, float* __restrict__ out)
{
    const int b = blockIdx.x;
    const int o = threadIdx.x >> 6;
    const int lane = threadIdx.x & 63;
    float acc = 0.f;
    for (int n = lane; n < F * M43; n += 64)
        acc += w_fc[o * (F * M43) + n] * S[b * (F * M43) + n];
    #pragma unroll
    for (int off = 32; off > 0; off >>= 1)
        acc += __shfl_down(acc, off, 64);
    if (lane == 0) out[b * 4 + o] = acc * (1.f / 501.f) + b_fc[o];
}

extern "C" void kernel_launch(void* const* d_in, const int* in_sizes, int n_in,
                              void* d_out, int out_size, void* d_ws, size_t ws_size,
                              hipStream_t stream) {
    const float* x    = (const float*)d_in[0];
    const float* w_t  = (const float*)d_in[1];
    const float* b_t  = (const float*)d_in[2];
    const float* g_t  = (const float*)d_in[3];
    const float* be_t = (const float*)d_in[4];
    const float* m_t  = (const float*)d_in[5];
    const float* v_t  = (const float*)d_in[6];
    const float* w_s  = (const float*)d_in[7];
    const float* b_s  = (const float*)d_in[8];
    const float* g_s  = (const float*)d_in[9];
    const float* be_s = (const float*)d_in[10];
    const float* m_s  = (const float*)d_in[11];
    const float* v_s  = (const float*)d_in[12];
    const float* w_c  = (const float*)d_in[13];
    const float* b_c  = (const float*)d_in[14];
    const float* g_c  = (const float*)d_in[15];
    const float* be_c = (const float*)d_in[16];
    const float* m_c  = (const float*)d_in[17];
    const float* v_c  = (const float*)d_in[18];
    const float* w_fc = (const float*)d_in[19];
    const float* b_fc = (const float*)d_in[20];

    float* ws  = (float*)d_ws;
    float* h2p = ws + H2P_OFF;
    float* P   = ws + P_OFF;
    float* Ep  = ws + EP_OFF;
    float* S   = ws + S_OFF;
    float* wtT = ws + WTT_OFF;
    float* wsT = ws + WST_OFF;
    float* wcT = ws + WCT_OFF;
    float* h1  = ws + H1_OFF;
    float* out = (float*)d_out;

    // slab the t-dimension so h1 fits whatever scratch we actually have
    long long availF = (long long)(ws_size / 4) - (long long)H1_OFF;
    long long tsl = availF / (B * FC);
    int TS;
    if (tsl >= T1) TS = T1;
    else { TS = (int)(tsl & ~63LL); if (TS < 64) TS = 64; }
    int nslab = (T1 + TS - 1) / TS;

    k_prep<<<dim3(112), 256, 0, stream>>>(w_t, w_s, w_c, wtT, wsT, wcT);

    for (int sl = 0; sl < nslab; ++sl) {
        int t_base = sl * TS;
        int TSeff = T1 - t_base; if (TSeff > TS) TSeff = TS;
        k_tconv<<<dim3((TSeff + 511) / 512, CH, B), 256, 0, stream>>>(
            x, wtT, b_t, g_t, be_t, m_t, v_t, h1, t_base, TS, TSeff);
        k_sconv<<<dim3((TSeff + 255) / 256, KSPLIT, B), 256, 0, stream>>>(
            h1, wsT, h2p, t_base, TS, TSeff);
    }

    k_pool<<<dim3(BF), 256, 0, stream>>>(h2p, b_s, g_s, be_s, m_s, v_s, P);
    k_qconv<<<dim3(NU2, FSPLIT, B), 256, 0, stream>>>(P, wcT, Ep);
    k_wins<<<dim3(BF), 256, 0, stream>>>(Ep, b_c, g_c, be_c, m_c, v_c, S);
    k_fc<<<dim3(B), 256, 0, stream>>>(S, w_fc, b_fc, out);
}

// Round 6
// 185.231 us; speedup vs baseline: 1.6171x; 1.6171x over previous
//
#include <hip/hip_runtime.h>

#define EPS 1e-5f
#define B 16
#define CH 22
#define T_IN 1001
#define F 36
#define RF 65
#define T1 937            // T_IN - RF + 1
#define FC 792            // F*CH
#define KW 99             // sconv per-wave K slice (FC/8)
#define UN 885            // valid u range for Q/E
#define PSTR 1072         // P row stride
#define PSPAN 304         // qconv staged span per f row
#define KS 15
#define GN 295
#define WN 129
#define M43 43
#define BF 576            // B*F

// workspace float offsets
#define H2_OFF  0                 // 576*937       =   539,712
#define P_OFF   539712            // + 576*1072    =   617,472
#define EP_OFF  1157184           // + 8*576*885   = 4,078,080
#define S_OFF   5235264           // + 576*43      =    24,768
#define WTT_OFF 5260032           // + 36*65       =     2,340
#define WST_OFF 5262372           // + 792*36      =    28,512
#define WCT_OFF 5290884           // + 36*15*36    =    19,440
#define BN_OFF  5310324           // + 6*36        =       216
#define H1_OFF  5310592           // h1 (slabbed if scratch is tight)

__device__ __forceinline__ float elu_f(float v) {
    return v > 0.f ? v : (__expf(v) - 1.f);
}

// ---- prep: transpose weights + precompute bn scale/offset ------------------
__global__ __launch_bounds__(256) void k_prep(
    const float* __restrict__ w_t, const float* __restrict__ w_s,
    const float* __restrict__ w_c,
    const float* __restrict__ b_t, const float* __restrict__ g_t,
    const float* __restrict__ be_t,const float* __restrict__ m_t,
    const float* __restrict__ v_t,
    const float* __restrict__ b_s, const float* __restrict__ g_s,
    const float* __restrict__ be_s,const float* __restrict__ m_s,
    const float* __restrict__ v_s,
    const float* __restrict__ b_c, const float* __restrict__ g_c,
    const float* __restrict__ be_c,const float* __restrict__ m_c,
    const float* __restrict__ v_c,
    float* __restrict__ wtT, float* __restrict__ wsT,
    float* __restrict__ wcT, float* __restrict__ bnz)
{
    int i = blockIdx.x * 256 + threadIdx.x;
    if (i < F * RF)     { int k = i / F,  fi = i % F; wtT[i] = w_t[fi * RF + k]; }
    if (i < FC * F)     { int fc = i / F, fo = i % F; wsT[i] = w_s[fo * FC + fc]; }
    if (i < F * KS * F) { int fk = i / F, fo = i % F; int f = fk / KS, k = fk % KS;
                          wcT[i] = w_c[(fo * F + f) * KS + k]; }
    if (i < F) {
        float s1 = g_t[i] * rsqrtf(v_t[i] + EPS);
        bnz[i]          = s1;
        bnz[F + i]      = (b_t[i] - m_t[i]) * s1 + be_t[i];
        float s2 = g_s[i] * rsqrtf(v_s[i] + EPS);
        bnz[2 * F + i]  = s2;
        bnz[3 * F + i]  = (b_s[i] - m_s[i]) * s2 + be_s[i];
        float s3 = g_c[i] * rsqrtf(v_c[i] + EPS);
        bnz[4 * F + i]  = s3;
        bnz[5 * F + i]  = (b_c[i] - m_c[i]) * s3 + be_c[i];
    }
}

// ---- K1a: temporal conv + bn + elu -> h1[b][fi][ch][t] (slab) --------------
// grid (ceil(TSeff/256), CH, B); 4 waves = 4 t-subchunks; wave = 64 t x 36 fi
__global__ __launch_bounds__(256) void k_tconv(
    const float* __restrict__ x, const float* __restrict__ wtT,
    const float* __restrict__ bnz, float* __restrict__ h1,
    int t_base, int TS, int TSeff)
{
    const int tloc = blockIdx.x * 256 + threadIdx.x;   // wave = 64 consecutive t
    const int b = blockIdx.z, ch = blockIdx.y;
    int t = t_base + tloc;
    int tc = t < (T1 - 1) ? t : (T1 - 1);
    const float* xp = x + (b * CH + ch) * T_IN + tc;

    float acc[F];
    #pragma unroll
    for (int j = 0; j < F; ++j) acc[j] = 0.f;

    #pragma unroll 5
    for (int k = 0; k < RF; ++k) {
        float xv = xp[k];                      // imm-offset, L1-hot, independent
        const float* wr = wtT + k * F;         // wave-uniform -> s_load x16
        #pragma unroll
        for (int j = 0; j < F; ++j) acc[j] += xv * wr[j];
    }

    if (tloc < TSeff) {
        #pragma unroll
        for (int j = 0; j < F; ++j) {
            float s1 = bnz[j], o1 = bnz[F + j];
            h1[((size_t)(b * F + j) * CH + ch) * TS + tloc] =
                elu_f(acc[j] * s1 + o1);
        }
    }
}

// ---- K1b: 1x1 spatial conv, in-block 8-way split-K + bn + elu -> h2 --------
// grid (ceil(TSeff/64), B); 512 thr = 8 waves = 8 K-slices of same 64 t
__global__ __launch_bounds__(512) void k_sconv(
    const float* __restrict__ h1, const float* __restrict__ wsT,
    const float* __restrict__ bnz, float* __restrict__ h2,
    int t_base, int TS, int TSeff)
{
    __shared__ float Ls[8 * F * 64];   // 73.7 KB
    const int tid = threadIdx.x;
    const int lane = tid & 63;
    const int w = __builtin_amdgcn_readfirstlane(tid >> 6);   // K-slice 0..7
    const int b = blockIdx.y;
    const int tl0 = blockIdx.x * 64;
    int tl = tl0 + lane;
    int tlc = tl < (TSeff - 1) ? tl : (TSeff - 1);

    const float* hq = h1 + ((size_t)b * FC + w * KW) * TS + tlc;
    const float* wb = wsT + (w * KW) * F;

    float acc[F];
    #pragma unroll
    for (int j = 0; j < F; ++j) acc[j] = 0.f;

    #pragma unroll 3
    for (int fc = 0; fc < KW; ++fc) {
        float hv = hq[(size_t)fc * TS];        // 256B coalesced, L2/L3
        const float* wr = wb + fc * F;         // wave-uniform -> s_load x16
        #pragma unroll
        for (int j = 0; j < F; ++j) acc[j] += hv * wr[j];
    }

    #pragma unroll
    for (int j = 0; j < F; ++j) Ls[(w * F + j) * 64 + lane] = acc[j];
    __syncthreads();

    for (int i = tid; i < F * 64; i += 512) {
        float s = 0.f;
        #pragma unroll
        for (int wq = 0; wq < 8; ++wq) s += Ls[wq * (F * 64) + i];
        int fo = i >> 6;
        int tloc2 = tl0 + (i & 63);
        int tg = t_base + tloc2;
        if (tloc2 < TSeff) {
            float s2 = bnz[2 * F + fo], o2 = bnz[3 * F + fo];
            h2[(b * F + fo) * T1 + tg] = elu_f(s * s2 + o2);
        }
    }
}

// ---- K1c: pool3 over h2 -> P[b][f][u] (padded row) -------------------------
__global__ __launch_bounds__(256) void k_pool(
    const float* __restrict__ h2, float* __restrict__ P)
{
    const int bf = blockIdx.x;
    const float* hr = h2 + (size_t)bf * T1;
    for (int u = threadIdx.x; u < PSTR; u += 256) {
        float a = 0.f;
        #pragma unroll
        for (int d = 0; d < 3; ++d) {
            int s = u + d; if (s > T1 - 1) s = T1 - 1;
            a += hr[s];
        }
        P[(size_t)bf * PSTR + u] = a * (1.f / 3.f);
    }
}

// ---- K2: dilated conv over P, 8 f-slices -> raw partials Ep ----------------
// grid (4, 8, B); 4 waves = 4 u-subchunks; wave = 64 u x 36 fo
__global__ __launch_bounds__(256) void k_qconv(
    const float* __restrict__ P, const float* __restrict__ wcT,
    float* __restrict__ Ep)
{
    __shared__ float Ps[5 * PSPAN];   // 6.1 KB
    const int tid = threadIdx.x;
    const int slice = blockIdx.y, b = blockIdx.z;
    const int u0 = blockIdx.x * 256;
    const int f_base = slice < 4 ? slice * 5 : 20 + (slice - 4) * 4;
    const int nf     = slice < 4 ? 5 : 4;

    for (int i = tid; i < nf * PSPAN; i += 256) {
        int fl = i / PSPAN, j = i % PSPAN;
        Ps[i] = P[(size_t)(b * F + f_base + fl) * PSTR + u0 + j];
    }
    __syncthreads();

    const int lu = tid;                        // wave = 64 consecutive u

    float acc[F];
    #pragma unroll
    for (int j = 0; j < F; ++j) acc[j] = 0.f;

    for (int fl = 0; fl < nf; ++fl) {
        const int pb = fl * PSPAN + lu;
        #pragma unroll 5
        for (int k = 0; k < KS; ++k) {
            float pv = Ps[pb + 3 * k];
            const float* wr = wcT + ((f_base + fl) * KS + k) * F;  // uniform
            #pragma unroll
            for (int j = 0; j < F; ++j) acc[j] += pv * wr[j];
        }
    }

    int u_g = u0 + lu;
    if (u_g < UN) {
        #pragma unroll
        for (int j = 0; j < F; ++j)
            Ep[(((size_t)slice * B + b) * F + j) * UN + u_g] = acc[j];
    }
}

// ---- K3: combine 8 Ep slices + bn_c + elu, window sums -> S ----------------
__global__ __launch_bounds__(256) void k_wins(
    const float* __restrict__ Ep, const float* __restrict__ bnz,
    float* __restrict__ S)
{
    __shared__ float Es[UN];
    __shared__ float G[GN];
    __shared__ float Ws[WN];
    const int tid = threadIdx.x;
    const int bf = blockIdx.x;
    const int f = bf % F;
    const float sc = bnz[4 * F + f];
    const float oc = bnz[5 * F + f];
    for (int i = tid; i < UN; i += 256) {
        float s = 0.f;
        #pragma unroll
        for (int sl = 0; sl < 8; ++sl)
            s += Ep[((size_t)sl * BF + bf) * UN + i];
        Es[i] = elu_f(s * sc + oc);
    }
    __syncthreads();
    for (int q = tid; q < GN; q += 256)
        G[q] = Es[3 * q] + Es[3 * q + 1] + Es[3 * q + 2];
    __syncthreads();
    if (tid < WN) {
        float a = 0.f;
        for (int q = tid; q < tid + 167; ++q) a += G[q];
        Ws[tid] = a;
    }
    __syncthreads();
    if (tid < M43)
        S[bf * M43 + tid] = (Ws[3 * tid] + Ws[3 * tid + 1] + Ws[3 * tid + 2]) * (1.f / 3.f);
}

// ---- K4: FC over summed features ------------------------------------------
__global__ __launch_bounds__(256) void k_fc(
    const float* __restrict__ S, const float* __restrict__ w_fc,
    const float* __restrict__ b_fc, float* __restrict__ out)
{
    const int b = blockIdx.x;
    const int o = threadIdx.x >> 6;
    const int lane = threadIdx.x & 63;
    float acc = 0.f;
    for (int n = lane; n < F * M43; n += 64)
        acc += w_fc[o * (F * M43) + n] * S[b * (F * M43) + n];
    #pragma unroll
    for (int off = 32; off > 0; off >>= 1)
        acc += __shfl_down(acc, off, 64);
    if (lane == 0) out[b * 4 + o] = acc * (1.f / 501.f) + b_fc[o];
}

extern "C" void kernel_launch(void* const* d_in, const int* in_sizes, int n_in,
                              void* d_out, int out_size, void* d_ws, size_t ws_size,
                              hipStream_t stream) {
    const float* x    = (const float*)d_in[0];
    const float* w_t  = (const float*)d_in[1];
    const float* b_t  = (const float*)d_in[2];
    const float* g_t  = (const float*)d_in[3];
    const float* be_t = (const float*)d_in[4];
    const float* m_t  = (const float*)d_in[5];
    const float* v_t  = (const float*)d_in[6];
    const float* w_s  = (const float*)d_in[7];
    const float* b_s  = (const float*)d_in[8];
    const float* g_s  = (const float*)d_in[9];
    const float* be_s = (const float*)d_in[10];
    const float* m_s  = (const float*)d_in[11];
    const float* v_s  = (const float*)d_in[12];
    const float* w_c  = (const float*)d_in[13];
    const float* b_c  = (const float*)d_in[14];
    const float* g_c  = (const float*)d_in[15];
    const float* be_c = (const float*)d_in[16];
    const float* m_c  = (const float*)d_in[17];
    const float* v_c  = (const float*)d_in[18];
    const float* w_fc = (const float*)d_in[19];
    const float* b_fc = (const float*)d_in[20];

    float* ws  = (float*)d_ws;
    float* h2  = ws + H2_OFF;
    float* P   = ws + P_OFF;
    float* Ep  = ws + EP_OFF;
    float* S   = ws + S_OFF;
    float* wtT = ws + WTT_OFF;
    float* wsT = ws + WST_OFF;
    float* wcT = ws + WCT_OFF;
    float* bnz = ws + BN_OFF;
    float* h1  = ws + H1_OFF;
    float* out = (float*)d_out;

    // slab the t-dimension so h1 fits whatever scratch we actually have
    long long availF = (long long)(ws_size / 4) - (long long)H1_OFF;
    long long tsl = availF / (B * FC);
    int TS;
    if (tsl >= T1) TS = T1;
    else { TS = (int)(tsl & ~63LL); if (TS < 64) TS = 64; }
    int nslab = (T1 + TS - 1) / TS;

    k_prep<<<dim3(112), 256, 0, stream>>>(
        w_t, w_s, w_c, b_t, g_t, be_t, m_t, v_t,
        b_s, g_s, be_s, m_s, v_s, b_c, g_c, be_c, m_c, v_c,
        wtT, wsT, wcT, bnz);

    for (int sl = 0; sl < nslab; ++sl) {
        int t_base = sl * TS;
        int TSeff = T1 - t_base; if (TSeff > TS) TSeff = TS;
        k_tconv<<<dim3((TSeff + 255) / 256, CH, B), 256, 0, stream>>>(
            x, wtT, bnz, h1, t_base, TS, TSeff);
        k_sconv<<<dim3((TSeff + 63) / 64, B), 512, 0, stream>>>(
            h1, wsT, bnz, h2, t_base, TS, TSeff);
    }

    k_pool<<<dim3(BF), 256, 0, stream>>>(h2, P);
    k_qconv<<<dim3(4, 8, B), 256, 0, stream>>>(P, wcT, Ep);
    k_wins<<<dim3(BF), 256, 0, stream>>>(Ep, bnz, S);
    k_fc<<<dim3(B), 256, 0, stream>>>(S, w_fc, b_fc, out);
}

// Round 7
// 179.490 us; speedup vs baseline: 1.6688x; 1.0320x over previous
//
#include <hip/hip_runtime.h>

#define EPS 1e-5f
#define B 16
#define CH 22
#define T_IN 1001
#define F 36
#define RF 65
#define T1 937            // T_IN - RF + 1
#define FC 792            // F*CH
#define KW 99             // sconv per-wave K slice (FC/8)
#define UN 885            // valid u range for Q/E
#define PSPAN 304         // qconv staged span per f row
#define KS 15
#define GN 295
#define WN 129
#define M43 43
#define BF 576            // B*F
#define FLAT 1548         // F*43

// workspace float offsets
#define H2_OFF  0                 // 576*937       =   539,712
#define EP_OFF  539712            // + 8*576*885   = 4,078,080
#define WTT_OFF 4617792           // + 36*65       =     2,340
#define WST_OFF 4620132           // + 792*36      =    28,512
#define WCT_OFF 4648644           // + 36*15*36    =    19,440
#define BN_OFF  4668084           // + 6*36        =       216
#define H1_OFF  4668352           // h1 (slabbed if scratch is tight)

__device__ __forceinline__ float elu_f(float v) {
    return v > 0.f ? v : (__expf(v) - 1.f);
}

// ---- prep: transpose weights + bn scale/offset + init out with bias --------
__global__ __launch_bounds__(256) void k_prep(
    const float* __restrict__ w_t, const float* __restrict__ w_s,
    const float* __restrict__ w_c,
    const float* __restrict__ b_t, const float* __restrict__ g_t,
    const float* __restrict__ be_t,const float* __restrict__ m_t,
    const float* __restrict__ v_t,
    const float* __restrict__ b_s, const float* __restrict__ g_s,
    const float* __restrict__ be_s,const float* __restrict__ m_s,
    const float* __restrict__ v_s,
    const float* __restrict__ b_c, const float* __restrict__ g_c,
    const float* __restrict__ be_c,const float* __restrict__ m_c,
    const float* __restrict__ v_c, const float* __restrict__ b_fc,
    float* __restrict__ wtT, float* __restrict__ wsT,
    float* __restrict__ wcT, float* __restrict__ bnz,
    float* __restrict__ out)
{
    int i = blockIdx.x * 256 + threadIdx.x;
    if (i < F * RF)     { int k = i / F,  fi = i % F; wtT[i] = w_t[fi * RF + k]; }
    if (i < FC * F)     { int fc = i / F, fo = i % F; wsT[i] = w_s[fo * FC + fc]; }
    if (i < F * KS * F) { int fk = i / F, fo = i % F; int f = fk / KS, k = fk % KS;
                          wcT[i] = w_c[(fo * F + f) * KS + k]; }
    if (i < F) {
        float s1 = g_t[i] * rsqrtf(v_t[i] + EPS);
        bnz[i]          = s1;
        bnz[F + i]      = (b_t[i] - m_t[i]) * s1 + be_t[i];
        float s2 = g_s[i] * rsqrtf(v_s[i] + EPS);
        bnz[2 * F + i]  = s2;
        bnz[3 * F + i]  = (b_s[i] - m_s[i]) * s2 + be_s[i];
        float s3 = g_c[i] * rsqrtf(v_c[i] + EPS);
        bnz[4 * F + i]  = s3;
        bnz[5 * F + i]  = (b_c[i] - m_c[i]) * s3 + be_c[i];
    }
    if (i < B * 4) out[i] = b_fc[i & 3];
}

// ---- K1a: temporal conv + bn + elu -> h1[b][fi][ch][t] (slab) --------------
// grid (ceil(TSeff/256), CH, B); 4 waves; wave = 64 consecutive t x 36 fi
__global__ __launch_bounds__(256) void k_tconv(
    const float* __restrict__ x, const float* __restrict__ wtT,
    const float* __restrict__ bnz, float* __restrict__ h1,
    int t_base, int TS, int TSeff)
{
    const int tloc = blockIdx.x * 256 + threadIdx.x;
    const int b = blockIdx.z, ch = blockIdx.y;
    int t = t_base + tloc;
    int tc = t < (T1 - 1) ? t : (T1 - 1);
    const float* xp = x + (b * CH + ch) * T_IN + tc;

    float acc[F];
    #pragma unroll
    for (int j = 0; j < F; ++j) acc[j] = 0.f;

    #pragma unroll 13
    for (int k = 0; k < RF; ++k) {
        float xv = xp[k];                      // imm-offset, L1-hot, independent
        const float* wr = wtT + k * F;         // wave-uniform -> wide s_load
        #pragma unroll
        for (int j = 0; j < F; ++j) acc[j] += xv * wr[j];
    }

    if (tloc < TSeff) {
        #pragma unroll
        for (int j = 0; j < F; ++j) {
            float s1 = bnz[j], o1 = bnz[F + j];
            h1[((size_t)(b * F + j) * CH + ch) * TS + tloc] =
                elu_f(acc[j] * s1 + o1);
        }
    }
}

// ---- K1b: 1x1 spatial conv, in-block 8-way split-K + bn + elu -> h2 --------
// grid (ceil(TSeff/64), B); 512 thr = 8 waves = 8 K-slices of same 64 t
__global__ __launch_bounds__(512) void k_sconv(
    const float* __restrict__ h1, const float* __restrict__ wsT,
    const float* __restrict__ bnz, float* __restrict__ h2,
    int t_base, int TS, int TSeff)
{
    __shared__ float Ls[8 * F * 64];   // 73.7 KB
    const int tid = threadIdx.x;
    const int lane = tid & 63;
    const int w = __builtin_amdgcn_readfirstlane(tid >> 6);   // K-slice 0..7
    const int b = blockIdx.y;
    const int tl0 = blockIdx.x * 64;
    int tl = tl0 + lane;
    int tlc = tl < (TSeff - 1) ? tl : (TSeff - 1);

    const float* hq = h1 + ((size_t)b * FC + w * KW) * TS + tlc;
    const float* wb = wsT + (w * KW) * F;

    float acc[F];
    #pragma unroll
    for (int j = 0; j < F; ++j) acc[j] = 0.f;

    #pragma unroll 9
    for (int fc = 0; fc < KW; ++fc) {
        float hv = hq[(size_t)fc * TS];        // 256B coalesced, L2/L3
        const float* wr = wb + fc * F;         // wave-uniform -> wide s_load
        #pragma unroll
        for (int j = 0; j < F; ++j) acc[j] += hv * wr[j];
    }

    #pragma unroll
    for (int j = 0; j < F; ++j) Ls[(w * F + j) * 64 + lane] = acc[j];
    __syncthreads();

    for (int i = tid; i < F * 64; i += 512) {
        float s = 0.f;
        #pragma unroll
        for (int wq = 0; wq < 8; ++wq) s += Ls[wq * (F * 64) + i];
        int fo = i >> 6;
        int tloc2 = tl0 + (i & 63);
        int tg = t_base + tloc2;
        if (tloc2 < TSeff) {
            float s2 = bnz[2 * F + fo], o2 = bnz[3 * F + fo];
            h2[(b * F + fo) * T1 + tg] = elu_f(s * s2 + o2);
        }
    }
}

// ---- K2: fused pool3 + dilated conv over h2 -> raw partials Ep -------------
// grid (4, 8, B); 4 waves = 4 u-subchunks; wave = 64 u x 36 fo
__global__ __launch_bounds__(256) void k_qconv(
    const float* __restrict__ h2, const float* __restrict__ wcT,
    float* __restrict__ Ep)
{
    __shared__ float Ps[5 * PSPAN];   // 6.1 KB
    const int tid = threadIdx.x;
    const int slice = blockIdx.y, b = blockIdx.z;
    const int u0 = blockIdx.x * 256;
    const int f_base = slice < 4 ? slice * 5 : 20 + (slice - 4) * 4;
    const int nf     = slice < 4 ? 5 : 4;

    for (int i = tid; i < nf * PSPAN; i += 256) {
        int fl = i / PSPAN, j = i % PSPAN;
        const float* hr = h2 + (size_t)(b * F + f_base + fl) * T1;
        int s = u0 + j;
        int s0 = s     < T1 - 1 ? s     : T1 - 1;
        int s1 = s + 1 < T1 - 1 ? s + 1 : T1 - 1;
        int s2 = s + 2 < T1 - 1 ? s + 2 : T1 - 1;
        Ps[i] = (hr[s0] + hr[s1] + hr[s2]) * (1.f / 3.f);
    }
    __syncthreads();

    const int lu = tid;                        // wave = 64 consecutive u

    float acc[F];
    #pragma unroll
    for (int j = 0; j < F; ++j) acc[j] = 0.f;

    for (int fl = 0; fl < nf; ++fl) {
        const int pb = fl * PSPAN + lu;
        #pragma unroll 5
        for (int k = 0; k < KS; ++k) {
            float pv = Ps[pb + 3 * k];
            const float* wr = wcT + ((f_base + fl) * KS + k) * F;  // uniform
            #pragma unroll
            for (int j = 0; j < F; ++j) acc[j] += pv * wr[j];
        }
    }

    int u_g = u0 + lu;
    if (u_g < UN) {
        #pragma unroll
        for (int j = 0; j < F; ++j)
            Ep[(((size_t)slice * B + b) * F + j) * UN + u_g] = acc[j];
    }
}

// ---- K3: combine Ep + bn_c + elu, window sums, fused FC -> atomicAdd out ---
__global__ __launch_bounds__(256) void k_wins(
    const float* __restrict__ Ep, const float* __restrict__ bnz,
    const float* __restrict__ w_fc, float* __restrict__ out)
{
    __shared__ float Es[UN];
    __shared__ float G[GN];
    __shared__ float Ws[WN];
    __shared__ float Sm[M43];
    const int tid = threadIdx.x;
    const int bf = blockIdx.x;
    const int b = bf / F, f = bf % F;
    const float sc = bnz[4 * F + f];
    const float oc = bnz[5 * F + f];
    for (int i = tid; i < UN; i += 256) {
        float s = 0.f;
        #pragma unroll
        for (int sl = 0; sl < 8; ++sl)
            s += Ep[((size_t)sl * BF + bf) * UN + i];
        Es[i] = elu_f(s * sc + oc);
    }
    __syncthreads();
    for (int q = tid; q < GN; q += 256)
        G[q] = Es[3 * q] + Es[3 * q + 1] + Es[3 * q + 2];
    __syncthreads();
    if (tid < WN) {
        float a = 0.f;
        for (int q = tid; q < tid + 167; ++q) a += G[q];
        Ws[tid] = a;
    }
    __syncthreads();
    if (tid < M43)
        Sm[tid] = (Ws[3 * tid] + Ws[3 * tid + 1] + Ws[3 * tid + 2]) * (1.f / 3.f);
    __syncthreads();
    if (tid < 4) {
        const float* wr = w_fc + tid * FLAT + f * M43;
        float a = 0.f;
        #pragma unroll 43
        for (int m = 0; m < M43; ++m) a += Sm[m] * wr[m];
        atomicAdd(&out[b * 4 + tid], a * (1.f / 501.f));
    }
}

extern "C" void kernel_launch(void* const* d_in, const int* in_sizes, int n_in,
                              void* d_out, int out_size, void* d_ws, size_t ws_size,
                              hipStream_t stream) {
    const float* x    = (const float*)d_in[0];
    const float* w_t  = (const float*)d_in[1];
    const float* b_t  = (const float*)d_in[2];
    const float* g_t  = (const float*)d_in[3];
    const float* be_t = (const float*)d_in[4];
    const float* m_t  = (const float*)d_in[5];
    const float* v_t  = (const float*)d_in[6];
    const float* w_s  = (const float*)d_in[7];
    const float* b_s  = (const float*)d_in[8];
    const float* g_s  = (const float*)d_in[9];
    const float* be_s = (const float*)d_in[10];
    const float* m_s  = (const float*)d_in[11];
    const float* v_s  = (const float*)d_in[12];
    const float* w_c  = (const float*)d_in[13];
    const float* b_c  = (const float*)d_in[14];
    const float* g_c  = (const float*)d_in[15];
    const float* be_c = (const float*)d_in[16];
    const float* m_c  = (const float*)d_in[17];
    const float* v_c  = (const float*)d_in[18];
    const float* w_fc = (const float*)d_in[19];
    const float* b_fc = (const float*)d_in[20];

    float* ws  = (float*)d_ws;
    float* h2  = ws + H2_OFF;
    float* Ep  = ws + EP_OFF;
    float* wtT = ws + WTT_OFF;
    float* wsT = ws + WST_OFF;
    float* wcT = ws + WCT_OFF;
    float* bnz = ws + BN_OFF;
    float* h1  = ws + H1_OFF;
    float* out = (float*)d_out;

    // slab the t-dimension so h1 fits whatever scratch we actually have
    long long availF = (long long)(ws_size / 4) - (long long)H1_OFF;
    long long tsl = availF / (B * FC);
    int TS;
    if (tsl >= T1) TS = T1;
    else { TS = (int)(tsl & ~63LL); if (TS < 64) TS = 64; }
    int nslab = (T1 + TS - 1) / TS;

    k_prep<<<dim3(112), 256, 0, stream>>>(
        w_t, w_s, w_c, b_t, g_t, be_t, m_t, v_t,
        b_s, g_s, be_s, m_s, v_s, b_c, g_c, be_c, m_c, v_c, b_fc,
        wtT, wsT, wcT, bnz, out);

    for (int sl = 0; sl < nslab; ++sl) {
        int t_base = sl * TS;
        int TSeff = T1 - t_base; if (TSeff > TS) TSeff = TS;
        k_tconv<<<dim3((TSeff + 255) / 256, CH, B), 256, 0, stream>>>(
            x, wtT, bnz, h1, t_base, TS, TSeff);
        k_sconv<<<dim3((TSeff + 63) / 64, B), 512, 0, stream>>>(
            h1, wsT, bnz, h2, t_base, TS, TSeff);
    }

    k_qconv<<<dim3(4, 8, B), 256, 0, stream>>>(h2, wcT, Ep);
    k_wins<<<dim3(BF), 256, 0, stream>>>(Ep, bnz, w_fc, out);
}